// Round 4
// baseline (113.569 us; speedup 1.0000x reference)
//
#include <hip/hip_runtime.h>
#include <math.h>

#define BB 4
#define C 64
#define O 64
#define H 128
#define W 128
#define K2 9
#define HW (H*W)
#define NOFF 36

typedef __bf16 bf16;
typedef bf16 bf16x8 __attribute__((ext_vector_type(8)));
typedef float f32x4 __attribute__((ext_vector_type(4)));
typedef unsigned short u16x8 __attribute__((ext_vector_type(8)));
typedef unsigned int u32x4 __attribute__((ext_vector_type(4)));

#define BSTR 55          /* bufF row stride (fp32 conv outputs) */
#define B2STR 19         /* packed-param row stride in uint4 units */
#define VSTR 36          /* valF row stride (fp32) */
#define SSTR 72          /* stage/val channel stride (bf16): 144B/px */
/* R16 LDS overlay (37,376 B), 32-px tile, 4 waves:
 *   [0 .. 14,688)   stage[3][34][72] (conv window; dies at conv barrier)
 *                   bufF[32][55]f32=7,040 (conv out; dies in precompute)
 *                   buf2[32][19]u32x4=9,728 (params; precompute->main)
 *                   valF[32... [64][36]f32=9,216 (final epilogue only)
 *   [9,728 .. 23,552)  val0[3][32][72] (main dbuf A)
 *   [23,552 .. 37,376) val1[3][32][72] (main dbuf B)
 * 4 blocks/CU (149 KB), 16 waves/CU; launch_bounds(256,4) -> VGPR cap 128
 * to hold 12 in-flight gather lines across the MFMA phase (T14 split). */
#define VAL_OFF 9728
#define VAL1_OFF 23552
#define SMEM_BYTES 37376
#define WFRAG 18432      /* bf16 per conv-half / group: 9*4*64*8 */
#define NW_TOTAL 73728

__device__ inline unsigned short f2h_bits(float f) {
  _Float16 h = (_Float16)f;
  return __builtin_bit_cast(unsigned short, h);
}
__device__ inline float h2f(unsigned short u) {
  return (float)__builtin_bit_cast(_Float16, u);
}

// ---------------------------------------------------------------------------
// K1 (validated R6-R12): NCHW fp32 -> NHWC bf16 transpose (1024 blocks) +
// weight swizzle to MFMA a-frag order (first 288 blocks).
//  frag[(ph*9+kk)*4+to][lane][j] = Wrow[m=to*16+(lane&15)][u=kk*32+(lane>>4)*8+j]
//  K order u = tap*32 + c'.  wfC: m<36 w_off, m<54 w_mask, else 0.
// ---------------------------------------------------------------------------
__global__ __launch_bounds__(256) void prep_all(
    const float* __restrict__ x, const float* __restrict__ w_main,
    const float* __restrict__ w_off, const float* __restrict__ w_mask,
    unsigned short* __restrict__ xT16, bf16* __restrict__ wfC,
    bf16* __restrict__ wfM) {
  __shared__ float tile[64][68];
  int tid = threadIdx.x;
  int b = blockIdx.x >> 8;
  int p0 = (blockIdx.x & 255) * 64;
#pragma unroll
  for (int it = 0; it < 4; ++it) {
    int c = it * 16 + (tid >> 4);
    int p4 = (tid & 15) * 4;
    *(f32x4*)&tile[c][p4] =
        *(const f32x4*)(x + (size_t)(b * C + c) * HW + p0 + p4);
  }
  __syncthreads();
#pragma unroll
  for (int it = 0; it < 2; ++it) {
    int t = it * 256 + tid;
    int p = t >> 3;
    int h8 = t & 7;
    u16x8 o;
#pragma unroll
    for (int j = 0; j < 8; ++j) {
      bf16 v = (bf16)tile[h8 * 8 + j][p];
      o[j] = __builtin_bit_cast(unsigned short, v);
    }
    *(u16x8*)&xT16[(size_t)(b * HW + p0 + p) * C + h8 * 8] = o;
  }
  int i = blockIdx.x * 256 + tid;
  if (i < NW_TOTAL) {
    int which = (i >= 36864);
    int ii = which ? i - 36864 : i;
    int j = ii & 7;
    int l = (ii >> 3) & 63;
    int rest = ii >> 9;
    int to = rest & 3;
    int kk = (rest >> 2) % 9;
    int ph = (rest >> 2) / 9;
    int m = to * 16 + (l & 15);
    int u = kk * 32 + (l >> 4) * 8 + j;
    int tap = u >> 5;
    int c1 = u & 31;
    if (!which) {
      int c = ph * 32 + c1;
      float v = (m < NOFF) ? w_off[(m * C + c) * K2 + tap]
                : (m < 54) ? w_mask[((m - NOFF) * C + c) * K2 + tap]
                           : 0.f;
      wfC[ii] = (bf16)v;
    } else {
      wfM[ii] = (bf16)w_main[(m * C + ph * 32 + c1) * K2 + tap];
    }
  }
}

// ---------------------------------------------------------------------------
// K2: fused deform, 32-px tiles x 256 threads (4 waves), grid 2048.
// R13: one 'to' (16 out-ch) per wave across both n-halves (weight a-frags
// loaded once per block).  R16: T14 async-split main loop -- chunk kc+1's 12
// corner loads are ISSUED before chunk kc's MFMA phase and consumed (lerp +
// val write) after it; val double-buffered, 3 barriers in main loop (was 5).
// vmcnt retires in issue order, so the gather wait hides under 24 MFMA +
// 12 ds_read_b128 + 12 a-frag loads.
// Conv: full-C 3x34 window staged ONCE (72-ch padded stride).
// mfma_f32_16x16x32_bf16 layouts (m89/m120 verified):
//   A: lane holds A[m=lane&15][k=(lane>>4)*8+j]
//   B: lane holds B[k=(lane>>4)*8+j][n=lane&15]
//   D: reg r holds D[m=(lane>>4)*4+r][n=lane&15]
// ---------------------------------------------------------------------------
__global__ __launch_bounds__(256, 4) void fused_deform(
    const bf16* __restrict__ xT, const bf16* __restrict__ wfC,
    const bf16* __restrict__ wfM, const float* __restrict__ b_off,
    const float* __restrict__ b_mask, float* __restrict__ out) {
  __shared__ __align__(16) char smem[SMEM_BYTES];
  bf16* stage = (bf16*)smem;              // [3][34][72] bf16 = 14,688 (conv)
  float* bufF = (float*)smem;             // [32][55] fp32 = 7,040 (conv out)
  u32x4* buf2 = (u32x4*)smem;             // [32][19] uint4 = 9,728 (params)
  float* valF = (float*)smem;             // [64][36] fp32 = 9,216 (out xpose)
  bf16* val0 = (bf16*)(smem + VAL_OFF);   // [3][32][72] bf16 = 13,824
  bf16* val1 = (bf16*)(smem + VAL1_OFF);  // [3][32][72] bf16 = 13,824

  const int tid = threadIdx.x;
  const int lane = tid & 63;
  const int wv = tid >> 6;        // 0..3
  const int n16 = lane & 15;
  const int q4 = lane >> 4;
  const int to = wv;              // this wave's out-channel 16-tile (0..3)
  const int pg = tid >> 3;        // gather pixel 0..31
  const int ch = tid & 7;         // gather 8-ch chunk 0..7 (abs ch = ch*8)

  // XCD-aware swizzle: XCD (blockIdx%8) works one image (2 MB bf16 in L2).
  const int g8 = blockIdx.x & 7;
  const int slot = blockIdx.x >> 3;      // 0..255
  const int b = g8 >> 1;
  const int ti = (g8 & 1) * 256 + slot;  // 0..511: 32-px tile index
  const int h0 = ti >> 2;
  const int w0 = (ti & 3) * 32;
  const bf16* xb = xT + (size_t)b * HW * C;

  bf16x8 zero8;
#pragma unroll
  for (int j = 0; j < 8; ++j) zero8[j] = (bf16)0.f;

  // ============ conv: stage full-C window once, 18 MFMA k-steps ============
#pragma unroll
  for (int it = 0; it < 4; ++it) {  // 816 = 3 rows x 34 px x 8 chunks
    int id = it * 256 + tid;
    if (id < 816) {
      int chk = id & 7;
      int rest = id >> 3;
      int wp = rest % 34;
      int r = rest / 34;
      int yy = h0 + r - 1;
      int xx = w0 + wp - 1;
      bf16x8 v = zero8;
      if ((unsigned)yy < (unsigned)H && (unsigned)xx < (unsigned)W)
        v = *(const bf16x8*)(xb + (size_t)((yy << 7) + xx) * C + chk * 8);
      *(bf16x8*)(stage + (r * 34 + wp) * SSTR + chk * 8) = v;
    }
  }
  __syncthreads();
  f32x4 accC[2] = {{0.f,0.f,0.f,0.f},{0.f,0.f,0.f,0.f}};
#pragma unroll 1
  for (int ph = 0; ph < 2; ++ph) {
#pragma unroll
    for (int kk = 0; kk < 9; ++kk) {
      // one a-frag load, used for both n-halves
      bf16x8 afr = *(const bf16x8*)(wfC +
          (size_t)(((ph * 9 + kk) * 4 + to) * 64 + lane) * 8);
#pragma unroll
      for (int nt = 0; nt < 2; ++nt) {
        bf16x8 bfr = *(const bf16x8*)(stage +
            ((kk / 3) * 34 + nt * 16 + n16 + kk % 3) * SSTR + ph * 32 + q4 * 8);
        accC[nt] = __builtin_amdgcn_mfma_f32_16x16x32_bf16(afr, bfr, accC[nt], 0, 0, 0);
      }
    }
  }
  __syncthreads();  // stage readers done before bufF overwrites

  // conv epilogue: bias + sigmoid -> bufF[p][o]
#pragma unroll
  for (int nt = 0; nt < 2; ++nt)
#pragma unroll
    for (int r = 0; r < 4; ++r) {
      int o = to * 16 + q4 * 4 + r;
      int p = nt * 16 + n16;
      float a = accC[nt][r];
      if (o < NOFF) {
        bufF[p * BSTR + o] = a + b_off[o];
      } else if (o < 54) {
        float s = a + b_mask[o - NOFF];
        bufF[p * BSTR + o] = 1.f / (1.f + __expf(-s));
      }
    }
  __syncthreads();

  // -------- bilinear precompute: 576 (p,gk) tasks -> packed uint4 --------
  unsigned int rW0[3], rW1[3], rCo[3];
#pragma unroll
  for (int it = 0; it < 3; ++it) {
    int t = it * 256 + tid;
    if (t < 576) {
      int p = t & 31;
      int gk = t >> 5;
      int g = gk / 9, tap = gk % 9;
      float offy = bufF[p * BSTR + 2 * gk];
      float offx = bufF[p * BSTR + 2 * gk + 1];
      float m = bufF[p * BSTR + NOFF + gk];
      float py = offy + (float)(h0 + tap / 3 - 1);
      float px = offx + (float)(w0 + p + tap % 3 - 1);
      float y0f = floorf(py), x0f = floorf(px);
      float wy1 = py - y0f, wx1 = px - x0f;
      float wy0 = 1.f - wy1, wx0 = 1.f - wx1;
      int y0 = (int)y0f, x0 = (int)x0f;
      int y1 = y0 + 1, x1 = x0 + 1;
      bool y0ok = (unsigned)y0 < (unsigned)H, y1ok = (unsigned)y1 < (unsigned)H;
      bool x0ok = (unsigned)x0 < (unsigned)W, x1ok = (unsigned)x1 < (unsigned)W;
      float w00 = (y0ok && x0ok) ? wy0 * wx0 * m : 0.f;
      float w01 = (y0ok && x1ok) ? wy0 * wx1 * m : 0.f;
      float w10 = (y1ok && x0ok) ? wy1 * wx0 * m : 0.f;
      float w11 = (y1ok && x1ok) ? wy1 * wx1 * m : 0.f;
      unsigned int y0c = (unsigned)min(max(y0, 0), H - 1);
      unsigned int y1c = (unsigned)min(max(y1, 0), H - 1);
      unsigned int x0c = (unsigned)min(max(x0, 0), W - 1);
      unsigned int x1c = (unsigned)min(max(x1, 0), W - 1);
      rW0[it] = (unsigned)f2h_bits(w00) | ((unsigned)f2h_bits(w01) << 16);
      rW1[it] = (unsigned)f2h_bits(w10) | ((unsigned)f2h_bits(w11) << 16);
      rCo[it] = y0c | (x0c << 8) | (y1c << 16) | (x1c << 24);
    }
  }
  __syncthreads();
#pragma unroll
  for (int it = 0; it < 3; ++it) {
    int t = it * 256 + tid;
    if (t < 576) {
      int p = t & 31;
      int gk = t >> 5;
      u32x4 pk = {rW0[it], rW1[it], rCo[it], 0u};
      buf2[p * B2STR + gk] = pk;
    }
  }
  __syncthreads();

  // -------- main deform: T14 async-split, val double-buffered ---------
  f32x4 accM[2] = {{0.f,0.f,0.f,0.f},{0.f,0.f,0.f,0.f}};
  const bf16* bb = xb + ch * 8;   // this thread's 8-channel slice (abs)
  const int gg = ch >> 2;          // group of this chunk

  // prologue: gather chunk 0 -> val0 (exposed once)
#pragma unroll
  for (int t = 0; t < 3; ++t) {
    u32x4 t4 = buf2[pg * B2STR + gg * 9 + t];
    float w00 = h2f(t4.x & 0xffff), w01 = h2f(t4.x >> 16);
    float w10 = h2f(t4.y & 0xffff), w11 = h2f(t4.y >> 16);
    int r0 = (int)(t4.z & 255) << 7;
    int x0 = (int)((t4.z >> 8) & 255);
    int r1 = (int)((t4.z >> 16) & 255) << 7;
    int x1 = (int)(t4.z >> 24);
    bf16x8 v00 = *(const bf16x8*)(bb + (size_t)(r0 + x0) * C);
    bf16x8 v01 = *(const bf16x8*)(bb + (size_t)(r0 + x1) * C);
    bf16x8 v10 = *(const bf16x8*)(bb + (size_t)(r1 + x0) * C);
    bf16x8 v11 = *(const bf16x8*)(bb + (size_t)(r1 + x1) * C);
    bf16x8 res;
#pragma unroll
    for (int j = 0; j < 8; ++j) {
      float v = (float)v00[j] * w00 + (float)v01[j] * w01 +
                (float)v10[j] * w10 + (float)v11[j] * w11;
      res[j] = (bf16)v;
    }
    *(bf16x8*)(val0 + (t * 32 + pg) * SSTR + ch * 8) = res;
  }
  __syncthreads();

#pragma unroll 1
  for (int kc = 0; kc < 3; ++kc) {
    bf16* cur = (kc & 1) ? val1 : val0;
    bf16* nxt = (kc & 1) ? val0 : val1;
    // (a) ISSUE next chunk's 12 corner loads; hold lines in regs
    bf16x8 hv[3][4];
    unsigned hwA[3], hwB[3];
    if (kc < 2) {
#pragma unroll
      for (int t = 0; t < 3; ++t) {
        u32x4 t4 = buf2[pg * B2STR + gg * 9 + (kc + 1) * 3 + t];
        hwA[t] = t4.x;
        hwB[t] = t4.y;
        int r0 = (int)(t4.z & 255) << 7;
        int x0 = (int)((t4.z >> 8) & 255);
        int r1 = (int)((t4.z >> 16) & 255) << 7;
        int x1 = (int)(t4.z >> 24);
        hv[t][0] = *(const bf16x8*)(bb + (size_t)(r0 + x0) * C);
        hv[t][1] = *(const bf16x8*)(bb + (size_t)(r0 + x1) * C);
        hv[t][2] = *(const bf16x8*)(bb + (size_t)(r1 + x0) * C);
        hv[t][3] = *(const bf16x8*)(bb + (size_t)(r1 + x1) * C);
      }
    }
    // (b) MFMA for chunk kc from cur (gather wait hides under this)
#pragma unroll
    for (int t = 0; t < 3; ++t) {
      int tap = kc * 3 + t;
#pragma unroll
      for (int g = 0; g < 2; ++g) {
        bf16x8 afr = *(const bf16x8*)(wfM + (size_t)g * WFRAG +
            (size_t)((tap * 4 + to) * 64 + lane) * 8);
#pragma unroll
        for (int nt = 0; nt < 2; ++nt) {
          bf16x8 bfr = *(const bf16x8*)(cur +
              (t * 32 + nt * 16 + n16) * SSTR + g * 32 + q4 * 8);
          accM[nt] = __builtin_amdgcn_mfma_f32_16x16x32_bf16(afr, bfr, accM[nt], 0, 0, 0);
        }
      }
    }
    // (c) lerp held lines -> nxt
    if (kc < 2) {
#pragma unroll
      for (int t = 0; t < 3; ++t) {
        float w00 = h2f(hwA[t] & 0xffff), w01 = h2f(hwA[t] >> 16);
        float w10 = h2f(hwB[t] & 0xffff), w11 = h2f(hwB[t] >> 16);
        bf16x8 res;
#pragma unroll
        for (int j = 0; j < 8; ++j) {
          float v = (float)hv[t][0][j] * w00 + (float)hv[t][1][j] * w01 +
                    (float)hv[t][2][j] * w10 + (float)hv[t][3][j] * w11;
          res[j] = (bf16)v;
        }
        *(bf16x8*)(nxt + (t * 32 + pg) * SSTR + ch * 8) = res;
      }
    }
    __syncthreads();
  }

  // -------- epilogue: LDS transpose -> coalesced NCHW dwordx4 stores -------
  // (loop-end barrier orders last val0 reads before valF overwrites buf2 area)
#pragma unroll
  for (int nt = 0; nt < 2; ++nt)
#pragma unroll
    for (int r = 0; r < 4; ++r)
      valF[(to * 16 + q4 * 4 + r) * VSTR + nt * 16 + n16] = accM[nt][r];
  __syncthreads();
  {
    float* ob = out + (size_t)b * O * HW + (h0 << 7) + w0;
#pragma unroll
    for (int it = 0; it < 2; ++it) {
      int id = it * 256 + tid;
      int o = id >> 3, seg = id & 7;
      f32x4 v = *(f32x4*)&valF[o * VSTR + seg * 4];
      *(f32x4*)&ob[(size_t)o * HW + seg * 4] = v;
    }
  }
}

// ---------------------------------------------------------------------------
extern "C" void kernel_launch(void* const* d_in, const int* in_sizes, int n_in,
                              void* d_out, int out_size, void* d_ws,
                              size_t ws_size, hipStream_t stream) {
  const float* x = (const float*)d_in[0];
  const float* w_main = (const float*)d_in[1];
  const float* w_off = (const float*)d_in[2];
  const float* b_off = (const float*)d_in[3];
  const float* w_mask = (const float*)d_in[4];
  const float* b_mask = (const float*)d_in[5];
  float* out = (float*)d_out;

  unsigned short* xT16 = (unsigned short*)d_ws;     // 8,388,608 B
  bf16* wfC = (bf16*)(xT16 + (size_t)BB * HW * C);  // 73,728 B
  bf16* wfM = wfC + 36864;                          // 73,728 B

  prep_all<<<1024, 256, 0, stream>>>(x, w_main, w_off, w_mask, xT16, wfC, wfM);
  fused_deform<<<2048, 256, 0, stream>>>((const bf16*)xT16, wfC, wfM, b_off,
                                         b_mask, out);
}

// Round 5
// 105.154 us; speedup vs baseline: 1.0800x; 1.0800x over previous
//
#include <hip/hip_runtime.h>
#include <math.h>

#define BB 4
#define C 64
#define O 64
#define H 128
#define W 128
#define K2 9
#define HW (H*W)
#define NOFF 36

typedef __bf16 bf16;
typedef bf16 bf16x8 __attribute__((ext_vector_type(8)));
typedef float f32x4 __attribute__((ext_vector_type(4)));
typedef unsigned short u16x8 __attribute__((ext_vector_type(8)));
typedef unsigned int u32x4 __attribute__((ext_vector_type(4)));

#define BSTR 55          /* bufF row stride (fp32 conv outputs) */
#define VSTR 36          /* valF row stride (fp32) */
/* R17 LDS diet -> 8 blocks/CU (32 waves/CU = HW max).
 * stage/val: stride 64 bf16 (128B/px, NO pad) + XOR chunk swizzle
 *   off(row,chunk) = row*64 + ((chunk^(row&7))*8)   [bf16 units]
 *   - gather writes (pg,ch): bank 4*(ch^pg) -> 8 req/bank = optimal
 *   - b128 frag reads (rows vary per lane): starts spread over all 8
 *     quads -> 8 req/bank = optimal; 16B alignment preserved.
 * buf2: 12B/entry packed as 3 flat u32 arrays (was u32x4, 16B).
 * Overlay (19,200 B total):
 *   [0 .. 12,288)   val[3][32][64]   (main loop)
 *   [0 .. 13,056)   stage[3][34][64] (conv; dies at conv-MFMA barrier)
 *   [0 ..  7,040)   bufF[32][55]f32  (conv out; dies in precompute)
 *   [0 ..  9,216)   valF[64][36]f32  (final epilogue only)
 *   [12,288..19,200) buf2a/b/c u32[576] each (precompute -> main)
 * 8 x 19,200 = 153,600 <= 160 KiB.  launch_bounds(256,8): VGPR cap 64
 * (compiler measured 60 on this structure in R16). */
#define VAL_BYTES 12288
#define B2A_OFF 12288
#define B2B_OFF 14592
#define B2C_OFF 16896
#define SMEM_BYTES 19200
#define WFRAG 18432      /* bf16 per conv-half / group: 9*4*64*8 */
#define NW_TOTAL 73728

__device__ inline unsigned short f2h_bits(float f) {
  _Float16 h = (_Float16)f;
  return __builtin_bit_cast(unsigned short, h);
}
__device__ inline float h2f(unsigned short u) {
  return (float)__builtin_bit_cast(_Float16, u);
}
/* swizzled LDS offset in bf16 units: row*64 + (chunk^(row&7))*8 */
__device__ inline int soff(int row, int chunk) {
  return row * 64 + ((chunk ^ (row & 7)) * 8);
}

// ---------------------------------------------------------------------------
// K1 (validated R6-R12): NCHW fp32 -> NHWC bf16 transpose (1024 blocks) +
// weight swizzle to MFMA a-frag order (first 288 blocks).
//  frag[(ph*9+kk)*4+to][lane][j] = Wrow[m=to*16+(lane&15)][u=kk*32+(lane>>4)*8+j]
//  K order u = tap*32 + c'.  wfC: m<36 w_off, m<54 w_mask, else 0.
// R17: tile stride 68->69 fixes 8-way LDS read conflict in the transpose
// (stride 68 f32 == 0 mod 32 banks across h8; 69 gives 2-way).
// ---------------------------------------------------------------------------
__global__ __launch_bounds__(256) void prep_all(
    const float* __restrict__ x, const float* __restrict__ w_main,
    const float* __restrict__ w_off, const float* __restrict__ w_mask,
    unsigned short* __restrict__ xT16, bf16* __restrict__ wfC,
    bf16* __restrict__ wfM) {
  __shared__ float tile[64][69];
  int tid = threadIdx.x;
  int b = blockIdx.x >> 8;
  int p0 = (blockIdx.x & 255) * 64;
#pragma unroll
  for (int it = 0; it < 4; ++it) {
    int c = it * 16 + (tid >> 4);
    int p4 = (tid & 15) * 4;
    *(f32x4*)&tile[c][p4] =
        *(const f32x4*)(x + (size_t)(b * C + c) * HW + p0 + p4);
  }
  __syncthreads();
#pragma unroll
  for (int it = 0; it < 2; ++it) {
    int t = it * 256 + tid;
    int p = t >> 3;
    int h8 = t & 7;
    u16x8 o;
#pragma unroll
    for (int j = 0; j < 8; ++j) {
      bf16 v = (bf16)tile[h8 * 8 + j][p];
      o[j] = __builtin_bit_cast(unsigned short, v);
    }
    *(u16x8*)&xT16[(size_t)(b * HW + p0 + p) * C + h8 * 8] = o;
  }
  int i = blockIdx.x * 256 + tid;
  if (i < NW_TOTAL) {
    int which = (i >= 36864);
    int ii = which ? i - 36864 : i;
    int j = ii & 7;
    int l = (ii >> 3) & 63;
    int rest = ii >> 9;
    int to = rest & 3;
    int kk = (rest >> 2) % 9;
    int ph = (rest >> 2) / 9;
    int m = to * 16 + (l & 15);
    int u = kk * 32 + (l >> 4) * 8 + j;
    int tap = u >> 5;
    int c1 = u & 31;
    if (!which) {
      int c = ph * 32 + c1;
      float v = (m < NOFF) ? w_off[(m * C + c) * K2 + tap]
                : (m < 54) ? w_mask[((m - NOFF) * C + c) * K2 + tap]
                           : 0.f;
      wfC[ii] = (bf16)v;
    } else {
      wfM[ii] = (bf16)w_main[(m * C + ph * 32 + c1) * K2 + tap];
    }
  }
}

// ---------------------------------------------------------------------------
// K2: fused deform, 32-px tiles x 256 threads (4 waves), grid 2048.
// R13: one 'to' (16 out-ch) per wave across both n-halves.
// R17: LDS diet (19,200 B) -> 8 blocks/CU = 32 waves/CU (HW max); main loop
// reverted to R14 structure (R16's register prefetch was sunk by the
// compiler -- VGPR_Count 60 -- and only cost occupancy).
// Conv: full-C 3x34 window staged ONCE (swizzled stride-64 layout).
// Main: per 3-tap chunk each thread issues 12 independent corner loads,
// lerps, writes val; MFMA from val.
// mfma_f32_16x16x32_bf16 layouts (m89/m120 verified):
//   A: lane holds A[m=lane&15][k=(lane>>4)*8+j]
//   B: lane holds B[k=(lane>>4)*8+j][n=lane&15]
//   D: reg r holds D[m=(lane>>4)*4+r][n=lane&15]
// ---------------------------------------------------------------------------
__global__ __launch_bounds__(256, 8) void fused_deform(
    const bf16* __restrict__ xT, const bf16* __restrict__ wfC,
    const bf16* __restrict__ wfM, const float* __restrict__ b_off,
    const float* __restrict__ b_mask, float* __restrict__ out) {
  __shared__ __align__(16) char smem[SMEM_BYTES];
  bf16* stage = (bf16*)smem;              // [3][34][64] swz = 13,056 (conv)
  float* bufF = (float*)smem;             // [32][55] fp32 = 7,040 (conv out)
  float* valF = (float*)smem;             // [64][36] fp32 = 9,216 (out xpose)
  bf16* val = (bf16*)smem;                // [3][32][64] swz = 12,288 (main)
  unsigned int* buf2a = (unsigned int*)(smem + B2A_OFF);  // w00|w01 f16x2
  unsigned int* buf2b = (unsigned int*)(smem + B2B_OFF);  // w10|w11 f16x2
  unsigned int* buf2c = (unsigned int*)(smem + B2C_OFF);  // y0|x0|y1|x1 u8x4

  const int tid = threadIdx.x;
  const int lane = tid & 63;
  const int wv = tid >> 6;        // 0..3
  const int n16 = lane & 15;
  const int q4 = lane >> 4;
  const int to = wv;              // this wave's out-channel 16-tile (0..3)
  const int pg = tid >> 3;        // gather pixel 0..31
  const int ch = tid & 7;         // gather 8-ch chunk 0..7 (abs ch = ch*8)

  // XCD-aware swizzle: XCD (blockIdx%8) works one image (2 MB bf16 in L2).
  const int g8 = blockIdx.x & 7;
  const int slot = blockIdx.x >> 3;      // 0..255
  const int b = g8 >> 1;
  const int ti = (g8 & 1) * 256 + slot;  // 0..511: 32-px tile index
  const int h0 = ti >> 2;
  const int w0 = (ti & 3) * 32;
  const bf16* xb = xT + (size_t)b * HW * C;

  bf16x8 zero8;
#pragma unroll
  for (int j = 0; j < 8; ++j) zero8[j] = (bf16)0.f;

  // ============ conv: stage full-C window once, 18 MFMA k-steps ============
#pragma unroll
  for (int it = 0; it < 4; ++it) {  // 816 = 3 rows x 34 px x 8 chunks
    int id = it * 256 + tid;
    if (id < 816) {
      int chk = id & 7;
      int rest = id >> 3;
      int wp = rest % 34;
      int r = rest / 34;
      int yy = h0 + r - 1;
      int xx = w0 + wp - 1;
      bf16x8 v = zero8;
      if ((unsigned)yy < (unsigned)H && (unsigned)xx < (unsigned)W)
        v = *(const bf16x8*)(xb + (size_t)((yy << 7) + xx) * C + chk * 8);
      *(bf16x8*)(stage + soff(r * 34 + wp, chk)) = v;
    }
  }
  __syncthreads();
  f32x4 accC[2] = {{0.f,0.f,0.f,0.f},{0.f,0.f,0.f,0.f}};
#pragma unroll 1
  for (int ph = 0; ph < 2; ++ph) {
#pragma unroll
    for (int kk = 0; kk < 9; ++kk) {
      // one a-frag load, used for both n-halves
      bf16x8 afr = *(const bf16x8*)(wfC +
          (size_t)(((ph * 9 + kk) * 4 + to) * 64 + lane) * 8);
#pragma unroll
      for (int nt = 0; nt < 2; ++nt) {
        int row = (kk / 3) * 34 + nt * 16 + n16 + kk % 3;
        bf16x8 bfr = *(const bf16x8*)(stage + soff(row, ph * 4 + q4));
        accC[nt] = __builtin_amdgcn_mfma_f32_16x16x32_bf16(afr, bfr, accC[nt], 0, 0, 0);
      }
    }
  }
  __syncthreads();  // stage readers done before bufF overwrites

  // conv epilogue: bias + sigmoid -> bufF[p][o]
#pragma unroll
  for (int nt = 0; nt < 2; ++nt)
#pragma unroll
    for (int r = 0; r < 4; ++r) {
      int o = to * 16 + q4 * 4 + r;
      int p = nt * 16 + n16;
      float a = accC[nt][r];
      if (o < NOFF) {
        bufF[p * BSTR + o] = a + b_off[o];
      } else if (o < 54) {
        float s = a + b_mask[o - NOFF];
        bufF[p * BSTR + o] = 1.f / (1.f + __expf(-s));
      }
    }
  __syncthreads();

  // ----- bilinear precompute: 576 (p,gk) tasks -> packed 12B params -----
  // bufF [0,7040) and buf2 [12288,19200) are disjoint: compute+write direct,
  // single barrier at the end (one fewer barrier than R16).
#pragma unroll
  for (int it = 0; it < 3; ++it) {
    int t = it * 256 + tid;
    if (t < 576) {
      int p = t & 31;
      int gk = t >> 5;
      int tap = gk % 9;
      float offy = bufF[p * BSTR + 2 * gk];
      float offx = bufF[p * BSTR + 2 * gk + 1];
      float m = bufF[p * BSTR + NOFF + gk];
      float py = offy + (float)(h0 + tap / 3 - 1);
      float px = offx + (float)(w0 + p + tap % 3 - 1);
      float y0f = floorf(py), x0f = floorf(px);
      float wy1 = py - y0f, wx1 = px - x0f;
      float wy0 = 1.f - wy1, wx0 = 1.f - wx1;
      int y0 = (int)y0f, x0 = (int)x0f;
      int y1 = y0 + 1, x1 = x0 + 1;
      bool y0ok = (unsigned)y0 < (unsigned)H, y1ok = (unsigned)y1 < (unsigned)H;
      bool x0ok = (unsigned)x0 < (unsigned)W, x1ok = (unsigned)x1 < (unsigned)W;
      float w00 = (y0ok && x0ok) ? wy0 * wx0 * m : 0.f;
      float w01 = (y0ok && x1ok) ? wy0 * wx1 * m : 0.f;
      float w10 = (y1ok && x0ok) ? wy1 * wx0 * m : 0.f;
      float w11 = (y1ok && x1ok) ? wy1 * wx1 * m : 0.f;
      unsigned int y0c = (unsigned)min(max(y0, 0), H - 1);
      unsigned int y1c = (unsigned)min(max(y1, 0), H - 1);
      unsigned int x0c = (unsigned)min(max(x0, 0), W - 1);
      unsigned int x1c = (unsigned)min(max(x1, 0), W - 1);
      int idx = p * 18 + gk;
      buf2a[idx] = (unsigned)f2h_bits(w00) | ((unsigned)f2h_bits(w01) << 16);
      buf2b[idx] = (unsigned)f2h_bits(w10) | ((unsigned)f2h_bits(w11) << 16);
      buf2c[idx] = y0c | (x0c << 8) | (y1c << 16) | (x1c << 24);
    }
  }
  __syncthreads();

  // -------- main deform: 3 tap-chunks, cooperative gather -> val -> MFMA ---
  f32x4 accM[2] = {{0.f,0.f,0.f,0.f},{0.f,0.f,0.f,0.f}};
  const bf16* bb = xb + ch * 8;   // this thread's 8-channel slice (abs)
  const int gg = ch >> 2;          // group of this chunk
#pragma unroll 1
  for (int kc = 0; kc < 3; ++kc) {
    if (kc) __syncthreads();  // val reuse vs previous MFMA readers
#pragma unroll
    for (int t = 0; t < 3; ++t) {  // 12 independent loads issued per thread
      int tap = kc * 3 + t;
      int idx = pg * 18 + gg * 9 + tap;
      unsigned wA = buf2a[idx];
      unsigned wB = buf2b[idx];
      unsigned co = buf2c[idx];
      float w00 = h2f(wA & 0xffff), w01 = h2f(wA >> 16);
      float w10 = h2f(wB & 0xffff), w11 = h2f(wB >> 16);
      int r0 = (int)(co & 255) << 7;
      int x0 = (int)((co >> 8) & 255);
      int r1 = (int)((co >> 16) & 255) << 7;
      int x1 = (int)(co >> 24);
      bf16x8 v00 = *(const bf16x8*)(bb + (size_t)(r0 + x0) * C);
      bf16x8 v01 = *(const bf16x8*)(bb + (size_t)(r0 + x1) * C);
      bf16x8 v10 = *(const bf16x8*)(bb + (size_t)(r1 + x0) * C);
      bf16x8 v11 = *(const bf16x8*)(bb + (size_t)(r1 + x1) * C);
      bf16x8 res;
#pragma unroll
      for (int j = 0; j < 8; ++j) {
        float v = (float)v00[j] * w00 + (float)v01[j] * w01 +
                  (float)v10[j] * w10 + (float)v11[j] * w11;
        res[j] = (bf16)v;
      }
      *(bf16x8*)(val + soff(t * 32 + pg, ch)) = res;
    }
    __syncthreads();
#pragma unroll
    for (int t = 0; t < 3; ++t) {
      int tap = kc * 3 + t;
#pragma unroll
      for (int g = 0; g < 2; ++g) {
        // one a-frag load, used for both n-halves
        bf16x8 afr = *(const bf16x8*)(wfM + (size_t)g * WFRAG +
            (size_t)((tap * 4 + to) * 64 + lane) * 8);
#pragma unroll
        for (int nt = 0; nt < 2; ++nt) {
          int row = t * 32 + nt * 16 + n16;
          bf16x8 bfr = *(const bf16x8*)(val + soff(row, g * 4 + q4));
          accM[nt] = __builtin_amdgcn_mfma_f32_16x16x32_bf16(afr, bfr, accM[nt], 0, 0, 0);
        }
      }
    }
  }

  // -------- epilogue: LDS transpose -> coalesced NCHW dwordx4 stores -------
  __syncthreads();  // val readers done before valF overwrites
#pragma unroll
  for (int nt = 0; nt < 2; ++nt)
#pragma unroll
    for (int r = 0; r < 4; ++r)
      valF[(to * 16 + q4 * 4 + r) * VSTR + nt * 16 + n16] = accM[nt][r];
  __syncthreads();
  {
    float* ob = out + (size_t)b * O * HW + (h0 << 7) + w0;
#pragma unroll
    for (int it = 0; it < 2; ++it) {
      int id = it * 256 + tid;
      int o = id >> 3, seg = id & 7;
      f32x4 v = *(f32x4*)&valF[o * VSTR + seg * 4];
      *(f32x4*)&ob[(size_t)o * HW + seg * 4] = v;
    }
  }
}

// ---------------------------------------------------------------------------
extern "C" void kernel_launch(void* const* d_in, const int* in_sizes, int n_in,
                              void* d_out, int out_size, void* d_ws,
                              size_t ws_size, hipStream_t stream) {
  const float* x = (const float*)d_in[0];
  const float* w_main = (const float*)d_in[1];
  const float* w_off = (const float*)d_in[2];
  const float* b_off = (const float*)d_in[3];
  const float* w_mask = (const float*)d_in[4];
  const float* b_mask = (const float*)d_in[5];
  float* out = (float*)d_out;

  unsigned short* xT16 = (unsigned short*)d_ws;     // 8,388,608 B
  bf16* wfC = (bf16*)(xT16 + (size_t)BB * HW * C);  // 73,728 B
  bf16* wfM = wfC + 36864;                          // 73,728 B

  prep_all<<<1024, 256, 0, stream>>>(x, w_main, w_off, w_mask, xT16, wfC, wfM);
  fused_deform<<<2048, 256, 0, stream>>>((const bf16*)xT16, wfC, wfM, b_off,
                                         b_mask, out);
}